// Round 1
// baseline (555.977 us; speedup 1.0000x reference)
//
#include <hip/hip_runtime.h>
#include <hip/hip_bf16.h>
#include <math.h>

#define TOK   4096
#define DIM   1024
#define DMLP  4096
#define NE    8
#define BM    128
#define BN    128
#define BN2   64
#define BK    64
#define PADMAX (TOK + NE * BM)   // 5120 padded slots
#define NTILES (PADMAX / BM)     // 40 row-tiles

typedef __attribute__((ext_vector_type(8))) short  short8;
typedef __attribute__((ext_vector_type(4))) float  float4v;
typedef __attribute__((ext_vector_type(4))) unsigned short ushort4v;

// async global->LDS, 16 B per lane; LDS dest is wave-uniform base + lane*16
#define ASYNC16(gp, lp) __builtin_amdgcn_global_load_lds( \
    (const __attribute__((address_space(1))) unsigned int*)(gp), \
    (__attribute__((address_space(3))) unsigned int*)(lp), 16, 0, 0)

// swizzled granule offset (shorts) for row R, k-chunk C (granule = 8 bf16 = 16 B)
#define FRAG_OFF(R, C) (((((R) << 3) + ((C) ^ ((R) & 7)))) << 3)

static __device__ __forceinline__ unsigned short f2bf(float f) {
  unsigned u = __float_as_uint(f);
  u += 0x7fffu + ((u >> 16) & 1u);
  return (unsigned short)(u >> 16);
}

// ---------------------------------------------------------------------------
// Kernel 1: group tokens by expert (single block).
// ---------------------------------------------------------------------------
__global__ void group_kernel(const int* __restrict__ eidx,
                             int* __restrict__ perm,
                             int* __restrict__ tile_e) {
  __shared__ int cnt[NE], off[NE], len[NE], cur[NE];
  const int tid = threadIdx.x;
  if (tid < NE) cnt[tid] = 0;
  __syncthreads();
  for (int i = tid; i < TOK; i += 256) atomicAdd(&cnt[eidx[i]], 1);
  __syncthreads();
  if (tid == 0) {
    int o = 0;
    for (int e = 0; e < NE; e++) {
      off[e] = o;
      len[e] = ((cnt[e] + BM - 1) / BM) * BM;
      cur[e] = o;
      o += len[e];
    }
  }
  __syncthreads();
  for (int s = tid; s < PADMAX; s += 256) perm[s] = -1;
  __syncthreads();
  for (int i = tid; i < TOK; i += 256) {
    const int e = eidx[i];
    const int p = atomicAdd(&cur[e], 1);
    perm[p] = i;
  }
  __syncthreads();
  for (int t = tid; t < NTILES; t += 256) {
    const int row = t * BM;
    int te = -1;
    for (int e = 0; e < NE; e++)
      if (row >= off[e] && row < off[e] + len[e]) te = e;
    tile_e[t] = te;
  }
}

// ---------------------------------------------------------------------------
// Kernel 2: pack weights to k-granule layout:
//   W [E][K][N] f32  ->  WT [E][K/8][N][8] bf16
// No LDS, float4-coalesced reads, fully contiguous 16B/lane writes.
// ---------------------------------------------------------------------------
__global__ __launch_bounds__(256)
void convpack_kernel(const float* __restrict__ W, unsigned short* __restrict__ WT,
                     int K, int N) {
  const int e  = blockIdx.z;
  const int kg = blockIdx.y;                       // 8-row k-granule index
  const int n0 = blockIdx.x * 1024 + threadIdx.x * 4;
  const float* Win = W + (size_t)e * K * N + (size_t)kg * 8 * N + n0;
  unsigned short* Wout = WT + (size_t)e * K * N + ((size_t)kg * N + n0) * 8;
  float4v v[8];
#pragma unroll
  for (int j = 0; j < 8; j++) v[j] = *(const float4v*)(Win + (size_t)j * N);
#pragma unroll
  for (int q = 0; q < 4; q++) {
    short8 g;
#pragma unroll
    for (int j = 0; j < 8; j++) g[j] = (short)f2bf(v[j][q]);
    *(short8*)(Wout + q * 8) = g;
  }
}

// ---------------------------------------------------------------------------
// Kernel 3: gather + convert x rows into permuted bf16 [PADMAX][DIM]
// ---------------------------------------------------------------------------
__global__ __launch_bounds__(256)
void xgather_kernel(const float* __restrict__ x, const int* __restrict__ perm,
                    unsigned short* __restrict__ xg) {
  const int slot = blockIdx.x;
  const int t    = perm[slot];
  const int tid  = threadIdx.x;
  ushort4v o = (ushort4v){0, 0, 0, 0};
  if (t >= 0) {
    const float4v v = *(const float4v*)(x + (size_t)t * DIM + tid * 4);
#pragma unroll
    for (int q = 0; q < 4; q++) o[q] = f2bf(v[q]);
  }
  *(ushort4v*)(xg + (size_t)slot * DIM + tid * 4) = o;
}

// ---------------------------------------------------------------------------
// Kernel 4: h = gelu(xg @ W1) -> bf16. 128x128 tile, BK=64, double-buffered
// LDS with raw barriers + counted prefetch overlap (T3-minimum schedule).
// Grid: (DMLP/BN, NTILES) so B-panel sharers land on the same XCD.
// ---------------------------------------------------------------------------
__global__ __launch_bounds__(256)
void gemm1_kernel(const unsigned short* __restrict__ xg,
                  const unsigned short* __restrict__ W1T,
                  const float* __restrict__ b1, const int* __restrict__ tile_e,
                  unsigned short* __restrict__ h) {
  const int bt = blockIdx.y;                 // row tile
  const int te = tile_e[bt];
  if (te < 0) return;
  const int n0 = blockIdx.x * BN;            // col tile
  const unsigned short* Asrc = xg + (size_t)bt * BM * DIM;
  const unsigned short* Bsrc = W1T + (size_t)te * DIM * DMLP;
  const int tid = threadIdx.x;

  __shared__ __align__(16) unsigned short As[2][BM * BK];   // 2 x 16 KB
  __shared__ __align__(16) unsigned short Bs[2][BN * BK];   // 2 x 16 KB

  // staging maps: issue t, this thread -> granule p = t*256+tid
  const unsigned short* ag[4];
  const unsigned short* bg[4];
  int lo[4];
#pragma unroll
  for (int t = 0; t < 4; t++) {
    const int p = t * 256 + tid;
    const int r = p >> 3;
    const int c = (p & 7) ^ (r & 7);
    ag[t] = Asrc + (size_t)r * DIM + c * 8;
    bg[t] = Bsrc + ((size_t)c * DMLP + n0 + r) * 8;   // granule layout
    lo[t] = p * 8;
  }

  const int wid = tid >> 6, lane = tid & 63;
  const int wm = (wid >> 1) * 64, wn = (wid & 1) * 64;
  const int l15 = lane & 15, quad = lane >> 4;

  float4v acc[4][4];
#pragma unroll
  for (int i = 0; i < 4; i++)
#pragma unroll
    for (int j = 0; j < 4; j++) acc[i][j] = (float4v){0.f, 0.f, 0.f, 0.f};

#define COMPUTE1(buf)                                                          \
  do {                                                                         \
    _Pragma("unroll")                                                          \
    for (int hh = 0; hh < 2; hh++) {                                           \
      short8 a[4], b[4];                                                       \
      const int C = hh * 4 + quad;                                             \
      _Pragma("unroll")                                                        \
      for (int i = 0; i < 4; i++)                                              \
        a[i] = *(const short8*)&As[buf][FRAG_OFF(wm + i * 16 + l15, C)];       \
      _Pragma("unroll")                                                        \
      for (int j = 0; j < 4; j++)                                              \
        b[j] = *(const short8*)&Bs[buf][FRAG_OFF(wn + j * 16 + l15, C)];       \
      _Pragma("unroll")                                                        \
      for (int i = 0; i < 4; i++)                                              \
        _Pragma("unroll")                                                      \
        for (int j = 0; j < 4; j++)                                            \
          acc[i][j] = __builtin_amdgcn_mfma_f32_16x16x32_bf16(a[i], b[j],      \
                                                              acc[i][j], 0, 0, 0); \
    }                                                                          \
  } while (0)

  // prologue: stage tile 0, drain, sync
#pragma unroll
  for (int t = 0; t < 4; t++) ASYNC16(ag[t], &As[0][lo[t]]);
#pragma unroll
  for (int t = 0; t < 4; t++) ASYNC16(bg[t], &Bs[0][lo[t]]);
  asm volatile("s_waitcnt vmcnt(0)" ::: "memory");
  __builtin_amdgcn_s_barrier();
  __builtin_amdgcn_sched_barrier(0);

  int cur = 0;
  for (int k0 = BK; k0 < DIM; k0 += BK) {
    const int nxt = cur ^ 1;
    // issue next tile's loads BEFORE computing current tile
#pragma unroll
    for (int t = 0; t < 4; t++) ASYNC16(ag[t] + k0, &As[nxt][lo[t]]);
#pragma unroll
    for (int t = 0; t < 4; t++) ASYNC16(bg[t] + (size_t)k0 * DMLP, &Bs[nxt][lo[t]]);
    COMPUTE1(cur);
    asm volatile("s_waitcnt vmcnt(0)" ::: "memory");  // next tile landed
    __builtin_amdgcn_s_barrier();
    __builtin_amdgcn_sched_barrier(0);
    cur = nxt;
  }
  COMPUTE1(cur);

#pragma unroll
  for (int i = 0; i < 4; i++) {
#pragma unroll
    for (int j = 0; j < 4; j++) {
      const int col = n0 + wn + j * 16 + l15;
      const float bias = b1[te * DMLP + col];
#pragma unroll
      for (int r = 0; r < 4; r++) {
        const int row = wm + i * 16 + quad * 4 + r;
        float v = acc[i][j][r] + bias;
        v = 0.5f * v * (1.0f + erff(v * 0.7071067811865475f));
        h[(size_t)(bt * BM + row) * DMLP + col] = f2bf(v);
      }
    }
  }
#undef COMPUTE1
}

// ---------------------------------------------------------------------------
// Kernel 5: out[tok] = h @ W2 + b2, scatter. 128x64 tile, BK=64,
// double-buffered with the same schedule. Grid: (DIM/BN2, NTILES).
// ---------------------------------------------------------------------------
__global__ __launch_bounds__(256)
void gemm2_kernel(const unsigned short* __restrict__ h,
                  const unsigned short* __restrict__ W2T,
                  const float* __restrict__ b2, const int* __restrict__ perm,
                  const int* __restrict__ tile_e, float* __restrict__ out) {
  const int bt = blockIdx.y;
  const int te = tile_e[bt];
  if (te < 0) return;
  const int n0 = blockIdx.x * BN2;
  const unsigned short* Asrc = h + (size_t)bt * BM * DMLP;
  const unsigned short* Bsrc = W2T + (size_t)te * DMLP * DIM;
  const int tid = threadIdx.x;

  __shared__ __align__(16) unsigned short As[2][BM * BK];    // 2 x 16 KB
  __shared__ __align__(16) unsigned short Bs[2][BN2 * BK];   // 2 x 8 KB

  const unsigned short* ag[4];
  const unsigned short* bg[2];
  int alo[4], blo[2];
#pragma unroll
  for (int t = 0; t < 4; t++) {
    const int p = t * 256 + tid;
    const int r = p >> 3;
    const int c = (p & 7) ^ (r & 7);
    ag[t] = Asrc + (size_t)r * DMLP + c * 8;
    alo[t] = p * 8;
  }
#pragma unroll
  for (int t = 0; t < 2; t++) {
    const int p = t * 256 + tid;
    const int r = p >> 3;
    const int c = (p & 7) ^ (r & 7);
    bg[t] = Bsrc + ((size_t)c * DIM + n0 + r) * 8;   // granule layout
    blo[t] = p * 8;
  }

  const int wid = tid >> 6, lane = tid & 63;
  const int wm = (wid >> 1) * 64, wn = (wid & 1) * 32;
  const int l15 = lane & 15, quad = lane >> 4;

  float4v acc[4][2];
#pragma unroll
  for (int i = 0; i < 4; i++)
#pragma unroll
    for (int j = 0; j < 2; j++) acc[i][j] = (float4v){0.f, 0.f, 0.f, 0.f};

#define COMPUTE2(buf)                                                          \
  do {                                                                         \
    _Pragma("unroll")                                                          \
    for (int hh = 0; hh < 2; hh++) {                                           \
      short8 a[4], b[2];                                                       \
      const int C = hh * 4 + quad;                                             \
      _Pragma("unroll")                                                        \
      for (int i = 0; i < 4; i++)                                              \
        a[i] = *(const short8*)&As[buf][FRAG_OFF(wm + i * 16 + l15, C)];       \
      _Pragma("unroll")                                                        \
      for (int j = 0; j < 2; j++)                                              \
        b[j] = *(const short8*)&Bs[buf][FRAG_OFF(wn + j * 16 + l15, C)];       \
      _Pragma("unroll")                                                        \
      for (int i = 0; i < 4; i++)                                              \
        _Pragma("unroll")                                                      \
        for (int j = 0; j < 2; j++)                                            \
          acc[i][j] = __builtin_amdgcn_mfma_f32_16x16x32_bf16(a[i], b[j],      \
                                                              acc[i][j], 0, 0, 0); \
    }                                                                          \
  } while (0)

  // prologue
#pragma unroll
  for (int t = 0; t < 4; t++) ASYNC16(ag[t], &As[0][alo[t]]);
#pragma unroll
  for (int t = 0; t < 2; t++) ASYNC16(bg[t], &Bs[0][blo[t]]);
  asm volatile("s_waitcnt vmcnt(0)" ::: "memory");
  __builtin_amdgcn_s_barrier();
  __builtin_amdgcn_sched_barrier(0);

  int cur = 0;
  for (int k0 = BK; k0 < DMLP; k0 += BK) {
    const int nxt = cur ^ 1;
#pragma unroll
    for (int t = 0; t < 4; t++) ASYNC16(ag[t] + k0, &As[nxt][alo[t]]);
#pragma unroll
    for (int t = 0; t < 2; t++) ASYNC16(bg[t] + (size_t)k0 * DIM, &Bs[nxt][blo[t]]);
    COMPUTE2(cur);
    asm volatile("s_waitcnt vmcnt(0)" ::: "memory");
    __builtin_amdgcn_s_barrier();
    __builtin_amdgcn_sched_barrier(0);
    cur = nxt;
  }
  COMPUTE2(cur);

#pragma unroll
  for (int i = 0; i < 4; i++) {
#pragma unroll
    for (int j = 0; j < 2; j++) {
      const int col = n0 + wn + j * 16 + l15;
      const float bias = b2[te * DIM + col];
#pragma unroll
      for (int r = 0; r < 4; r++) {
        const int row  = wm + i * 16 + quad * 4 + r;
        const int slot = bt * BM + row;
        const int t    = perm[slot];
        if (t >= 0) out[(size_t)t * DIM + col] = acc[i][j][r] + bias;
      }
    }
  }
#undef COMPUTE2
}

// ---------------------------------------------------------------------------
extern "C" void kernel_launch(void* const* d_in, const int* in_sizes, int n_in,
                              void* d_out, int out_size, void* d_ws, size_t ws_size,
                              hipStream_t stream) {
  const float* x    = (const float*)d_in[0];
  const int*   eidx = (const int*)d_in[1];
  const float* W1   = (const float*)d_in[2];
  const float* b1   = (const float*)d_in[3];
  const float* W2   = (const float*)d_in[4];
  const float* b2   = (const float*)d_in[5];
  float* out = (float*)d_out;

  char* ws = (char*)d_ws;
  int* perm   = (int*)ws;                              // PADMAX ints
  int* tile_e = (int*)(ws + PADMAX * sizeof(int));     // NTILES ints
  unsigned short* xg  = (unsigned short*)(ws + 32768);                      // 10 MB
  unsigned short* h   = (unsigned short*)(ws + 32768 + 10485760);           // 40 MB
  unsigned short* W1T = (unsigned short*)(ws + 32768 + 10485760 + 41943040);// 64 MB
  unsigned short* W2T = (unsigned short*)((char*)W1T + 67108864);           // 64 MB

  group_kernel<<<1, 256, 0, stream>>>(eidx, perm, tile_e);
  convpack_kernel<<<dim3(DMLP / 1024, DIM / 8, NE), 256, 0, stream>>>(W1, W1T, DIM, DMLP);
  convpack_kernel<<<dim3(DIM / 1024, DMLP / 8, NE), 256, 0, stream>>>(W2, W2T, DMLP, DIM);
  xgather_kernel<<<PADMAX, 256, 0, stream>>>(x, perm, xg);
  gemm1_kernel<<<dim3(DMLP / BN, NTILES), 256, 0, stream>>>(xg, W1T, b1, tile_e, h);
  gemm2_kernel<<<dim3(DIM / BN2, NTILES), 256, 0, stream>>>(h, W2T, b2, perm, tile_e, out);
}

// Round 2
// 545.589 us; speedup vs baseline: 1.0190x; 1.0190x over previous
//
#include <hip/hip_runtime.h>
#include <hip/hip_bf16.h>
#include <math.h>

#define TOK   4096
#define DIM   1024
#define DMLP  4096
#define NE    8
#define BM    128
#define BN    128
#define BN2   64
#define BK    64
#define PADMAX (TOK + NE * BM)   // 5120 padded slots
#define NTILES (PADMAX / BM)     // 40 row-tiles

typedef __attribute__((ext_vector_type(8))) short  short8;
typedef __attribute__((ext_vector_type(4))) float  float4v;
typedef __attribute__((ext_vector_type(4))) unsigned short ushort4v;

// async global->LDS, 16 B per lane; LDS dest is wave-uniform base + lane*16
#define ASYNC16(gp, lp) __builtin_amdgcn_global_load_lds( \
    (const __attribute__((address_space(1))) unsigned int*)(gp), \
    (__attribute__((address_space(3))) unsigned int*)(lp), 16, 0, 0)

// swizzled granule offset (shorts) for row R, k-chunk C (granule = 8 bf16 = 16 B)
#define FRAG_OFF(R, C) (((((R) << 3) + ((C) ^ ((R) & 7)))) << 3)

static __device__ __forceinline__ unsigned short f2bf(float f) {
  unsigned u = __float_as_uint(f);
  u += 0x7fffu + ((u >> 16) & 1u);
  return (unsigned short)(u >> 16);
}

// ---------------------------------------------------------------------------
// Kernel 1: group tokens by expert (single block).
// ---------------------------------------------------------------------------
__global__ void group_kernel(const int* __restrict__ eidx,
                             int* __restrict__ perm,
                             int* __restrict__ tile_e) {
  __shared__ int cnt[NE], off[NE], len[NE], cur[NE];
  const int tid = threadIdx.x;
  if (tid < NE) cnt[tid] = 0;
  __syncthreads();
  for (int i = tid; i < TOK; i += 256) atomicAdd(&cnt[eidx[i]], 1);
  __syncthreads();
  if (tid == 0) {
    int o = 0;
    for (int e = 0; e < NE; e++) {
      off[e] = o;
      len[e] = ((cnt[e] + BM - 1) / BM) * BM;
      cur[e] = o;
      o += len[e];
    }
  }
  __syncthreads();
  for (int s = tid; s < PADMAX; s += 256) perm[s] = -1;
  __syncthreads();
  for (int i = tid; i < TOK; i += 256) {
    const int e = eidx[i];
    const int p = atomicAdd(&cur[e], 1);
    perm[p] = i;
  }
  __syncthreads();
  for (int t = tid; t < NTILES; t += 256) {
    const int row = t * BM;
    int te = -1;
    for (int e = 0; e < NE; e++)
      if (row >= off[e] && row < off[e] + len[e]) te = e;
    tile_e[t] = te;
  }
}

// ---------------------------------------------------------------------------
// Kernel 2: transpose + convert weights: W [E][K][N] f32 -> WT [E][N][K] bf16
// (round-0 proven version: GEMM-side staging needs [N][K] for coalescing,
// since global_load_lds pins the LDS destination to lane order)
// ---------------------------------------------------------------------------
__global__ __launch_bounds__(256)
void convtrans_kernel(const float* __restrict__ W, unsigned short* __restrict__ WT,
                      int K, int N) {
  __shared__ unsigned short T[64][66];
  const int e  = blockIdx.z;
  const int k0 = blockIdx.y * 64, n0 = blockIdx.x * 64;
  const float* Win = W + (size_t)e * K * N;
  unsigned short* Wout = WT + (size_t)e * K * N;
  const int tid = threadIdx.x;
  const int nl  = tid & 63;
  const int kb  = (tid >> 6) * 16;
#pragma unroll
  for (int r = 0; r < 16; r++) {
    const int kl = kb + r;
    T[nl][kl] = f2bf(Win[(size_t)(k0 + kl) * N + n0 + nl]);
  }
  __syncthreads();
  const int kc = (tid & 31) * 2;
  const int nb = tid >> 5;
#pragma unroll
  for (int r = 0; r < 8; r++) {
    const int nl2 = nb + r * 8;
    const unsigned v = *(const unsigned*)&T[nl2][kc];
    *(unsigned*)&Wout[(size_t)(n0 + nl2) * K + k0 + kc] = v;
  }
}

// ---------------------------------------------------------------------------
// Kernel 3: gather + convert x rows into permuted bf16 [PADMAX][DIM]
// ---------------------------------------------------------------------------
__global__ __launch_bounds__(256)
void xgather_kernel(const float* __restrict__ x, const int* __restrict__ perm,
                    unsigned short* __restrict__ xg) {
  const int slot = blockIdx.x;
  const int t    = perm[slot];
  const int tid  = threadIdx.x;
  ushort4v o = (ushort4v){0, 0, 0, 0};
  if (t >= 0) {
    const float4v v = *(const float4v*)(x + (size_t)t * DIM + tid * 4);
#pragma unroll
    for (int q = 0; q < 4; q++) o[q] = f2bf(v[q]);
  }
  *(ushort4v*)(xg + (size_t)slot * DIM + tid * 4) = o;
}

// ---------------------------------------------------------------------------
// Kernel 4: h = gelu(xg @ W1T^T + b1) -> bf16. 128x128 tile, BK=64,
// double-buffered LDS + raw barriers (one barrier per K-step, loads in
// flight across the MFMA block). Grid: (DMLP/BN, NTILES) for XCD L2 reuse.
// ---------------------------------------------------------------------------
__global__ __launch_bounds__(256)
void gemm1_kernel(const unsigned short* __restrict__ xg,
                  const unsigned short* __restrict__ W1T,
                  const float* __restrict__ b1, const int* __restrict__ tile_e,
                  unsigned short* __restrict__ h) {
  const int bt = blockIdx.y;                 // row tile
  const int te = tile_e[bt];
  if (te < 0) return;
  const int n0 = blockIdx.x * BN;            // col tile
  const unsigned short* Asrc = xg + (size_t)bt * BM * DIM;
  const unsigned short* Bsrc = W1T + (size_t)te * DIM * DMLP + (size_t)n0 * DIM;
  const int tid = threadIdx.x;

  __shared__ __align__(16) unsigned short As[2][BM * BK];   // 2 x 16 KB
  __shared__ __align__(16) unsigned short Bs[2][BN * BK];   // 2 x 16 KB

  // staging maps: issue t, this thread -> granule p = t*256+tid
  const unsigned short* ag[4];
  const unsigned short* bg[4];
  int lo[4];
#pragma unroll
  for (int t = 0; t < 4; t++) {
    const int p = t * 256 + tid;
    const int r = p >> 3;
    const int c = (p & 7) ^ (r & 7);
    ag[t] = Asrc + (size_t)r * DIM + c * 8;
    bg[t] = Bsrc + (size_t)r * DIM + c * 8;   // [N][K] rows: 128B segments
    lo[t] = p * 8;
  }

  const int wid = tid >> 6, lane = tid & 63;
  const int wm = (wid >> 1) * 64, wn = (wid & 1) * 64;
  const int l15 = lane & 15, quad = lane >> 4;

  float4v acc[4][4];
#pragma unroll
  for (int i = 0; i < 4; i++)
#pragma unroll
    for (int j = 0; j < 4; j++) acc[i][j] = (float4v){0.f, 0.f, 0.f, 0.f};

#define COMPUTE1(buf)                                                          \
  do {                                                                         \
    _Pragma("unroll")                                                          \
    for (int hh = 0; hh < 2; hh++) {                                           \
      short8 a[4], b[4];                                                       \
      const int C = hh * 4 + quad;                                             \
      _Pragma("unroll")                                                        \
      for (int i = 0; i < 4; i++)                                              \
        a[i] = *(const short8*)&As[buf][FRAG_OFF(wm + i * 16 + l15, C)];       \
      _Pragma("unroll")                                                        \
      for (int j = 0; j < 4; j++)                                              \
        b[j] = *(const short8*)&Bs[buf][FRAG_OFF(wn + j * 16 + l15, C)];       \
      _Pragma("unroll")                                                        \
      for (int i = 0; i < 4; i++)                                              \
        _Pragma("unroll")                                                      \
        for (int j = 0; j < 4; j++)                                            \
          acc[i][j] = __builtin_amdgcn_mfma_f32_16x16x32_bf16(a[i], b[j],      \
                                                              acc[i][j], 0, 0, 0); \
    }                                                                          \
  } while (0)

  // prologue: stage tile 0, drain, sync
#pragma unroll
  for (int t = 0; t < 4; t++) ASYNC16(ag[t], &As[0][lo[t]]);
#pragma unroll
  for (int t = 0; t < 4; t++) ASYNC16(bg[t], &Bs[0][lo[t]]);
  asm volatile("s_waitcnt vmcnt(0)" ::: "memory");
  __builtin_amdgcn_s_barrier();
  __builtin_amdgcn_sched_barrier(0);

  int cur = 0;
  for (int k0 = BK; k0 < DIM; k0 += BK) {
    const int nxt = cur ^ 1;
    // issue next tile's loads BEFORE computing current tile
#pragma unroll
    for (int t = 0; t < 4; t++) ASYNC16(ag[t] + k0, &As[nxt][lo[t]]);
#pragma unroll
    for (int t = 0; t < 4; t++) ASYNC16(bg[t] + k0, &Bs[nxt][lo[t]]);
    COMPUTE1(cur);
    asm volatile("s_waitcnt vmcnt(0)" ::: "memory");  // next tile landed
    __builtin_amdgcn_s_barrier();
    __builtin_amdgcn_sched_barrier(0);
    cur = nxt;
  }
  COMPUTE1(cur);

#pragma unroll
  for (int i = 0; i < 4; i++) {
#pragma unroll
    for (int j = 0; j < 4; j++) {
      const int col = n0 + wn + j * 16 + l15;
      const float bias = b1[te * DMLP + col];
#pragma unroll
      for (int r = 0; r < 4; r++) {
        const int row = wm + i * 16 + quad * 4 + r;
        float v = acc[i][j][r] + bias;
        v = 0.5f * v * (1.0f + erff(v * 0.7071067811865475f));
        h[(size_t)(bt * BM + row) * DMLP + col] = f2bf(v);
      }
    }
  }
#undef COMPUTE1
}

// ---------------------------------------------------------------------------
// Kernel 5: out[tok] = h @ W2T^T + b2, scatter. 128x64 tile, BK=64,
// double-buffered, same schedule. Grid: (DIM/BN2, NTILES).
// ---------------------------------------------------------------------------
__global__ __launch_bounds__(256)
void gemm2_kernel(const unsigned short* __restrict__ h,
                  const unsigned short* __restrict__ W2T,
                  const float* __restrict__ b2, const int* __restrict__ perm,
                  const int* __restrict__ tile_e, float* __restrict__ out) {
  const int bt = blockIdx.y;
  const int te = tile_e[bt];
  if (te < 0) return;
  const int n0 = blockIdx.x * BN2;
  const unsigned short* Asrc = h + (size_t)bt * BM * DMLP;
  const unsigned short* Bsrc = W2T + (size_t)te * DMLP * DIM + (size_t)n0 * DMLP;
  const int tid = threadIdx.x;

  __shared__ __align__(16) unsigned short As[2][BM * BK];    // 2 x 16 KB
  __shared__ __align__(16) unsigned short Bs[2][BN2 * BK];   // 2 x 8 KB

  const unsigned short* ag[4];
  const unsigned short* bg[2];
  int alo[4], blo[2];
#pragma unroll
  for (int t = 0; t < 4; t++) {
    const int p = t * 256 + tid;
    const int r = p >> 3;
    const int c = (p & 7) ^ (r & 7);
    ag[t] = Asrc + (size_t)r * DMLP + c * 8;
    alo[t] = p * 8;
  }
#pragma unroll
  for (int t = 0; t < 2; t++) {
    const int p = t * 256 + tid;
    const int r = p >> 3;
    const int c = (p & 7) ^ (r & 7);
    bg[t] = Bsrc + (size_t)r * DMLP + c * 8;   // [N][K] rows: 128B segments
    blo[t] = p * 8;
  }

  const int wid = tid >> 6, lane = tid & 63;
  const int wm = (wid >> 1) * 64, wn = (wid & 1) * 32;
  const int l15 = lane & 15, quad = lane >> 4;

  float4v acc[4][2];
#pragma unroll
  for (int i = 0; i < 4; i++)
#pragma unroll
    for (int j = 0; j < 2; j++) acc[i][j] = (float4v){0.f, 0.f, 0.f, 0.f};

#define COMPUTE2(buf)                                                          \
  do {                                                                         \
    _Pragma("unroll")                                                          \
    for (int hh = 0; hh < 2; hh++) {                                           \
      short8 a[4], b[2];                                                       \
      const int C = hh * 4 + quad;                                             \
      _Pragma("unroll")                                                        \
      for (int i = 0; i < 4; i++)                                              \
        a[i] = *(const short8*)&As[buf][FRAG_OFF(wm + i * 16 + l15, C)];       \
      _Pragma("unroll")                                                        \
      for (int j = 0; j < 2; j++)                                              \
        b[j] = *(const short8*)&Bs[buf][FRAG_OFF(wn + j * 16 + l15, C)];       \
      _Pragma("unroll")                                                        \
      for (int i = 0; i < 4; i++)                                              \
        _Pragma("unroll")                                                      \
        for (int j = 0; j < 2; j++)                                            \
          acc[i][j] = __builtin_amdgcn_mfma_f32_16x16x32_bf16(a[i], b[j],      \
                                                              acc[i][j], 0, 0, 0); \
    }                                                                          \
  } while (0)

  // prologue
#pragma unroll
  for (int t = 0; t < 4; t++) ASYNC16(ag[t], &As[0][alo[t]]);
#pragma unroll
  for (int t = 0; t < 2; t++) ASYNC16(bg[t], &Bs[0][blo[t]]);
  asm volatile("s_waitcnt vmcnt(0)" ::: "memory");
  __builtin_amdgcn_s_barrier();
  __builtin_amdgcn_sched_barrier(0);

  int cur = 0;
  for (int k0 = BK; k0 < DMLP; k0 += BK) {
    const int nxt = cur ^ 1;
#pragma unroll
    for (int t = 0; t < 4; t++) ASYNC16(ag[t] + k0, &As[nxt][alo[t]]);
#pragma unroll
    for (int t = 0; t < 2; t++) ASYNC16(bg[t] + k0, &Bs[nxt][blo[t]]);
    COMPUTE2(cur);
    asm volatile("s_waitcnt vmcnt(0)" ::: "memory");
    __builtin_amdgcn_s_barrier();
    __builtin_amdgcn_sched_barrier(0);
    cur = nxt;
  }
  COMPUTE2(cur);

#pragma unroll
  for (int i = 0; i < 4; i++) {
#pragma unroll
    for (int j = 0; j < 2; j++) {
      const int col = n0 + wn + j * 16 + l15;
      const float bias = b2[te * DIM + col];
#pragma unroll
      for (int r = 0; r < 4; r++) {
        const int row  = wm + i * 16 + quad * 4 + r;
        const int slot = bt * BM + row;
        const int t    = perm[slot];
        if (t >= 0) out[(size_t)t * DIM + col] = acc[i][j][r] + bias;
      }
    }
  }
#undef COMPUTE2
}

// ---------------------------------------------------------------------------
extern "C" void kernel_launch(void* const* d_in, const int* in_sizes, int n_in,
                              void* d_out, int out_size, void* d_ws, size_t ws_size,
                              hipStream_t stream) {
  const float* x    = (const float*)d_in[0];
  const int*   eidx = (const int*)d_in[1];
  const float* W1   = (const float*)d_in[2];
  const float* b1   = (const float*)d_in[3];
  const float* W2   = (const float*)d_in[4];
  const float* b2   = (const float*)d_in[5];
  float* out = (float*)d_out;

  char* ws = (char*)d_ws;
  int* perm   = (int*)ws;                              // PADMAX ints
  int* tile_e = (int*)(ws + PADMAX * sizeof(int));     // NTILES ints
  unsigned short* xg  = (unsigned short*)(ws + 32768);                      // 10 MB
  unsigned short* h   = (unsigned short*)(ws + 32768 + 10485760);           // 40 MB
  unsigned short* W1T = (unsigned short*)(ws + 32768 + 10485760 + 41943040);// 64 MB
  unsigned short* W2T = (unsigned short*)((char*)W1T + 67108864);           // 64 MB

  group_kernel<<<1, 256, 0, stream>>>(eidx, perm, tile_e);
  convtrans_kernel<<<dim3(DMLP / 64, DIM / 64, NE), 256, 0, stream>>>(W1, W1T, DIM, DMLP);
  convtrans_kernel<<<dim3(DIM / 64, DMLP / 64, NE), 256, 0, stream>>>(W2, W2T, DMLP, DIM);
  xgather_kernel<<<PADMAX, 256, 0, stream>>>(x, perm, xg);
  gemm1_kernel<<<dim3(DMLP / BN, NTILES), 256, 0, stream>>>(xg, W1T, b1, tile_e, h);
  gemm2_kernel<<<dim3(DIM / BN2, NTILES), 256, 0, stream>>>(h, W2T, b2, perm, tile_e, out);
}

// Round 3
// 504.085 us; speedup vs baseline: 1.1029x; 1.0823x over previous
//
#include <hip/hip_runtime.h>
#include <hip/hip_bf16.h>
#include <math.h>

#define TOK   4096
#define DIM   1024
#define DMLP  4096
#define NE    8
#define BM    128
#define BN    128
#define BK    64
#define PADMAX (TOK + NE * BM)   // 5120 padded slots
#define NTILES (PADMAX / BM)     // 40 row-tiles

typedef __attribute__((ext_vector_type(8))) short  short8;
typedef __attribute__((ext_vector_type(4))) float  float4v;
typedef __attribute__((ext_vector_type(4))) unsigned short ushort4v;

// async global->LDS, 16 B per lane; LDS dest is wave-uniform base + lane*16
#define ASYNC16(gp, lp) __builtin_amdgcn_global_load_lds( \
    (const __attribute__((address_space(1))) unsigned int*)(gp), \
    (__attribute__((address_space(3))) unsigned int*)(lp), 16, 0, 0)

// swizzled granule offset (shorts) for row R, k-chunk C (granule = 8 bf16 = 16 B)
#define FRAG_OFF(R, C) (((((R) << 3) + ((C) ^ ((R) & 7)))) << 3)

static __device__ __forceinline__ unsigned short f2bf(float f) {
  unsigned u = __float_as_uint(f);
  u += 0x7fffu + ((u >> 16) & 1u);
  return (unsigned short)(u >> 16);
}

// ---------------------------------------------------------------------------
// Kernel 1: group tokens by expert (single block).
// ---------------------------------------------------------------------------
__global__ void group_kernel(const int* __restrict__ eidx,
                             int* __restrict__ perm,
                             int* __restrict__ tile_e) {
  __shared__ int cnt[NE], off[NE], len[NE], cur[NE];
  const int tid = threadIdx.x;
  if (tid < NE) cnt[tid] = 0;
  __syncthreads();
  for (int i = tid; i < TOK; i += 256) atomicAdd(&cnt[eidx[i]], 1);
  __syncthreads();
  if (tid == 0) {
    int o = 0;
    for (int e = 0; e < NE; e++) {
      off[e] = o;
      len[e] = ((cnt[e] + BM - 1) / BM) * BM;
      cur[e] = o;
      o += len[e];
    }
  }
  __syncthreads();
  for (int s = tid; s < PADMAX; s += 256) perm[s] = -1;
  __syncthreads();
  for (int i = tid; i < TOK; i += 256) {
    const int e = eidx[i];
    const int p = atomicAdd(&cur[e], 1);
    perm[p] = i;
  }
  __syncthreads();
  for (int t = tid; t < NTILES; t += 256) {
    const int row = t * BM;
    int te = -1;
    for (int e = 0; e < NE; e++)
      if (row >= off[e] && row < off[e] + len[e]) te = e;
    tile_e[t] = te;
  }
}

// ---------------------------------------------------------------------------
// Kernel 2: transpose + convert weights: W [E][K][N] f32 -> WT [E][N][K] bf16
// ---------------------------------------------------------------------------
__global__ __launch_bounds__(256)
void convtrans_kernel(const float* __restrict__ W, unsigned short* __restrict__ WT,
                      int K, int N) {
  __shared__ unsigned short T[64][66];
  const int e  = blockIdx.z;
  const int k0 = blockIdx.y * 64, n0 = blockIdx.x * 64;
  const float* Win = W + (size_t)e * K * N;
  unsigned short* Wout = WT + (size_t)e * K * N;
  const int tid = threadIdx.x;
  const int nl  = tid & 63;
  const int kb  = (tid >> 6) * 16;
#pragma unroll
  for (int r = 0; r < 16; r++) {
    const int kl = kb + r;
    T[nl][kl] = f2bf(Win[(size_t)(k0 + kl) * N + n0 + nl]);
  }
  __syncthreads();
  const int kc = (tid & 31) * 2;
  const int nb = tid >> 5;
#pragma unroll
  for (int r = 0; r < 8; r++) {
    const int nl2 = nb + r * 8;
    const unsigned v = *(const unsigned*)&T[nl2][kc];
    *(unsigned*)&Wout[(size_t)(n0 + nl2) * K + k0 + kc] = v;
  }
}

// ---------------------------------------------------------------------------
// Kernel 3: gather + convert x rows into permuted bf16 [PADMAX][DIM]
// ---------------------------------------------------------------------------
__global__ __launch_bounds__(256)
void xgather_kernel(const float* __restrict__ x, const int* __restrict__ perm,
                    unsigned short* __restrict__ xg) {
  const int slot = blockIdx.x;
  const int t    = perm[slot];
  const int tid  = threadIdx.x;
  ushort4v o = (ushort4v){0, 0, 0, 0};
  if (t >= 0) {
    const float4v v = *(const float4v*)(x + (size_t)t * DIM + tid * 4);
#pragma unroll
    for (int q = 0; q < 4; q++) o[q] = f2bf(v[q]);
  }
  *(ushort4v*)(xg + (size_t)slot * DIM + tid * 4) = o;
}

// ---------------------------------------------------------------------------
// Kernel 4: h = gelu(xg @ W1T^T + b1) -> bf16. 128x128 tile, BK=64,
// round-0 proven single-buffer schedule (32 KB LDS, 5 blocks/CU,
// inter-block latency overlap). Grid: (DMLP/BN, NTILES) col-fastest so the
// 40 blocks sharing a B panel land on one XCD (FETCH 165->75 MB, proven r2).
// ---------------------------------------------------------------------------
__global__ __launch_bounds__(256)
void gemm1_kernel(const unsigned short* __restrict__ xg,
                  const unsigned short* __restrict__ W1T,
                  const float* __restrict__ b1, const int* __restrict__ tile_e,
                  unsigned short* __restrict__ h) {
  const int bt = blockIdx.y;                 // row tile
  const int te = tile_e[bt];
  if (te < 0) return;
  const int n0 = blockIdx.x * BN;            // col tile
  const unsigned short* Asrc = xg + (size_t)bt * BM * DIM;
  const unsigned short* Bsrc = W1T + (size_t)te * DIM * DMLP + (size_t)n0 * DIM;
  const int tid = threadIdx.x;

  __shared__ __align__(16) unsigned short As[BM * BK];   // 16 KB
  __shared__ __align__(16) unsigned short Bs[BN * BK];   // 16 KB

  // staging maps: issue t, this thread -> granule p = t*256+tid
  const unsigned short* ag[4];
  const unsigned short* bg[4];
  int lo[4];
#pragma unroll
  for (int t = 0; t < 4; t++) {
    const int p = t * 256 + tid;
    const int r = p >> 3;
    const int c = (p & 7) ^ (r & 7);
    ag[t] = Asrc + (size_t)r * DIM + c * 8;
    bg[t] = Bsrc + (size_t)r * DIM + c * 8;   // [N][K] rows: 128B segments
    lo[t] = p * 8;
  }

  const int wid = tid >> 6, lane = tid & 63;
  const int wm = (wid >> 1) * 64, wn = (wid & 1) * 64;
  const int l15 = lane & 15, quad = lane >> 4;

  float4v acc[4][4];
#pragma unroll
  for (int i = 0; i < 4; i++)
#pragma unroll
    for (int j = 0; j < 4; j++) acc[i][j] = (float4v){0.f, 0.f, 0.f, 0.f};

  for (int k0 = 0; k0 < DIM; k0 += BK) {
#pragma unroll
    for (int t = 0; t < 4; t++) ASYNC16(ag[t] + k0, &As[lo[t]]);
#pragma unroll
    for (int t = 0; t < 4; t++) ASYNC16(bg[t] + k0, &Bs[lo[t]]);
    __syncthreads();

#pragma unroll
    for (int hh = 0; hh < 2; hh++) {
      short8 a[4], b[4];
      const int C = hh * 4 + quad;
#pragma unroll
      for (int i = 0; i < 4; i++) a[i] = *(const short8*)&As[FRAG_OFF(wm + i * 16 + l15, C)];
#pragma unroll
      for (int j = 0; j < 4; j++) b[j] = *(const short8*)&Bs[FRAG_OFF(wn + j * 16 + l15, C)];
#pragma unroll
      for (int i = 0; i < 4; i++)
#pragma unroll
        for (int j = 0; j < 4; j++)
          acc[i][j] = __builtin_amdgcn_mfma_f32_16x16x32_bf16(a[i], b[j], acc[i][j], 0, 0, 0);
    }
    __syncthreads();
  }

#pragma unroll
  for (int i = 0; i < 4; i++) {
#pragma unroll
    for (int j = 0; j < 4; j++) {
      const int col = n0 + wn + j * 16 + l15;
      const float bias = b1[te * DMLP + col];
#pragma unroll
      for (int r = 0; r < 4; r++) {
        const int row = wm + i * 16 + quad * 4 + r;
        float v = acc[i][j][r] + bias;
        v = 0.5f * v * (1.0f + erff(v * 0.7071067811865475f));
        h[(size_t)(bt * BM + row) * DMLP + col] = f2bf(v);
      }
    }
  }
}

// ---------------------------------------------------------------------------
// Kernel 5: out[tok] = h @ W2T^T + b2, scatter. WIDENED to 128x128 tile
// (was 128x64): 2x MFMA per K-step against the same per-step latency, and
// half the latency-exposed block-steps. Same proven single-buffer schedule.
// Grid: (DIM/BN = 8, NTILES) col-fastest -> 40 B-panel sharers per XCD.
// ---------------------------------------------------------------------------
__global__ __launch_bounds__(256)
void gemm2_kernel(const unsigned short* __restrict__ h,
                  const unsigned short* __restrict__ W2T,
                  const float* __restrict__ b2, const int* __restrict__ perm,
                  const int* __restrict__ tile_e, float* __restrict__ out) {
  const int bt = blockIdx.y;
  const int te = tile_e[bt];
  if (te < 0) return;
  const int n0 = blockIdx.x * BN;
  const unsigned short* Asrc = h + (size_t)bt * BM * DMLP;
  const unsigned short* Bsrc = W2T + (size_t)te * DMLP * DIM + (size_t)n0 * DMLP;
  const int tid = threadIdx.x;

  __shared__ __align__(16) unsigned short As[BM * BK];   // 16 KB
  __shared__ __align__(16) unsigned short Bs[BN * BK];   // 16 KB

  const unsigned short* ag[4];
  const unsigned short* bg[4];
  int lo[4];
#pragma unroll
  for (int t = 0; t < 4; t++) {
    const int p = t * 256 + tid;
    const int r = p >> 3;
    const int c = (p & 7) ^ (r & 7);
    ag[t] = Asrc + (size_t)r * DMLP + c * 8;
    bg[t] = Bsrc + (size_t)r * DMLP + c * 8;   // [N][K] rows: 128B segments
    lo[t] = p * 8;
  }

  const int wid = tid >> 6, lane = tid & 63;
  const int wm = (wid >> 1) * 64, wn = (wid & 1) * 64;
  const int l15 = lane & 15, quad = lane >> 4;

  float4v acc[4][4];
#pragma unroll
  for (int i = 0; i < 4; i++)
#pragma unroll
    for (int j = 0; j < 4; j++) acc[i][j] = (float4v){0.f, 0.f, 0.f, 0.f};

  for (int k0 = 0; k0 < DMLP; k0 += BK) {
#pragma unroll
    for (int t = 0; t < 4; t++) ASYNC16(ag[t] + k0, &As[lo[t]]);
#pragma unroll
    for (int t = 0; t < 4; t++) ASYNC16(bg[t] + k0, &Bs[lo[t]]);
    __syncthreads();

#pragma unroll
    for (int hh = 0; hh < 2; hh++) {
      short8 a[4], b[4];
      const int C = hh * 4 + quad;
#pragma unroll
      for (int i = 0; i < 4; i++) a[i] = *(const short8*)&As[FRAG_OFF(wm + i * 16 + l15, C)];
#pragma unroll
      for (int j = 0; j < 4; j++) b[j] = *(const short8*)&Bs[FRAG_OFF(wn + j * 16 + l15, C)];
#pragma unroll
      for (int i = 0; i < 4; i++)
#pragma unroll
        for (int j = 0; j < 4; j++)
          acc[i][j] = __builtin_amdgcn_mfma_f32_16x16x32_bf16(a[i], b[j], acc[i][j], 0, 0, 0);
    }
    __syncthreads();
  }

#pragma unroll
  for (int i = 0; i < 4; i++) {
#pragma unroll
    for (int j = 0; j < 4; j++) {
      const int col = n0 + wn + j * 16 + l15;
      const float bias = b2[te * DIM + col];
#pragma unroll
      for (int r = 0; r < 4; r++) {
        const int row  = wm + i * 16 + quad * 4 + r;
        const int slot = bt * BM + row;
        const int t    = perm[slot];
        if (t >= 0) out[(size_t)t * DIM + col] = acc[i][j][r] + bias;
      }
    }
  }
}

// ---------------------------------------------------------------------------
extern "C" void kernel_launch(void* const* d_in, const int* in_sizes, int n_in,
                              void* d_out, int out_size, void* d_ws, size_t ws_size,
                              hipStream_t stream) {
  const float* x    = (const float*)d_in[0];
  const int*   eidx = (const int*)d_in[1];
  const float* W1   = (const float*)d_in[2];
  const float* b1   = (const float*)d_in[3];
  const float* W2   = (const float*)d_in[4];
  const float* b2   = (const float*)d_in[5];
  float* out = (float*)d_out;

  char* ws = (char*)d_ws;
  int* perm   = (int*)ws;                              // PADMAX ints
  int* tile_e = (int*)(ws + PADMAX * sizeof(int));     // NTILES ints
  unsigned short* xg  = (unsigned short*)(ws + 32768);                      // 10 MB
  unsigned short* h   = (unsigned short*)(ws + 32768 + 10485760);           // 40 MB
  unsigned short* W1T = (unsigned short*)(ws + 32768 + 10485760 + 41943040);// 64 MB
  unsigned short* W2T = (unsigned short*)((char*)W1T + 67108864);           // 64 MB

  group_kernel<<<1, 256, 0, stream>>>(eidx, perm, tile_e);
  convtrans_kernel<<<dim3(DMLP / 64, DIM / 64, NE), 256, 0, stream>>>(W1, W1T, DIM, DMLP);
  convtrans_kernel<<<dim3(DIM / 64, DMLP / 64, NE), 256, 0, stream>>>(W2, W2T, DMLP, DIM);
  xgather_kernel<<<PADMAX, 256, 0, stream>>>(x, perm, xg);
  gemm1_kernel<<<dim3(DMLP / BN, NTILES), 256, 0, stream>>>(xg, W1T, b1, tile_e, h);
  gemm2_kernel<<<dim3(DIM / BN, NTILES), 256, 0, stream>>>(h, W2T, b2, perm, tile_e, out);
}

// Round 4
// 493.632 us; speedup vs baseline: 1.1263x; 1.0212x over previous
//
#include <hip/hip_runtime.h>
#include <hip/hip_bf16.h>
#include <math.h>

#define TOK   4096
#define DIM   1024
#define DMLP  4096
#define NE    8
#define BM    128
#define BN    128
#define BK    64
#define PADMAX (TOK + NE * BM)   // 5120 padded slots
#define NTILES (PADMAX / BM)     // 40 row-tiles

typedef __attribute__((ext_vector_type(8))) short  short8;
typedef __attribute__((ext_vector_type(4))) float  float4v;
typedef __attribute__((ext_vector_type(4))) unsigned short ushort4v;
typedef __attribute__((ext_vector_type(2))) unsigned long long ull2;

// async global->LDS, 16 B per lane; LDS dest is wave-uniform base + lane*16
#define ASYNC16(gp, lp) __builtin_amdgcn_global_load_lds( \
    (const __attribute__((address_space(1))) unsigned int*)(gp), \
    (__attribute__((address_space(3))) unsigned int*)(lp), 16, 0, 0)

// swizzled granule offset (shorts) for row R, k-chunk C (granule = 8 bf16 = 16 B)
#define FRAG_OFF(R, C) (((((R) << 3) + ((C) ^ ((R) & 7)))) << 3)

static __device__ __forceinline__ unsigned short f2bf(float f) {
  unsigned u = __float_as_uint(f);
  u += 0x7fffu + ((u >> 16) & 1u);
  return (unsigned short)(u >> 16);
}

// exact-erf GELU via Abramowitz&Stegun 7.1.26 (|err| < 1.5e-7, ~13 VALU
// vs ~40 for libm erff)
static __device__ __forceinline__ float gelu_erf(float v) {
  const float x = fabsf(v) * 0.70710678118654752f;
  const float t = __builtin_amdgcn_rcpf(1.0f + 0.3275911f * x);
  const float poly = ((((1.061405429f * t - 1.453152027f) * t + 1.421413741f) * t
                       - 0.284496736f) * t + 0.254829592f) * t;
  const float erf_abs = 1.0f - poly * __expf(-x * x);
  return 0.5f * v * (1.0f + copysignf(erf_abs, v));
}

// ---------------------------------------------------------------------------
// Kernel 1: group tokens by expert (single block).
// ---------------------------------------------------------------------------
__global__ void group_kernel(const int* __restrict__ eidx,
                             int* __restrict__ perm,
                             int* __restrict__ tile_e) {
  __shared__ int cnt[NE], off[NE], len[NE], cur[NE];
  const int tid = threadIdx.x;
  if (tid < NE) cnt[tid] = 0;
  __syncthreads();
  for (int i = tid; i < TOK; i += 256) atomicAdd(&cnt[eidx[i]], 1);
  __syncthreads();
  if (tid == 0) {
    int o = 0;
    for (int e = 0; e < NE; e++) {
      off[e] = o;
      len[e] = ((cnt[e] + BM - 1) / BM) * BM;
      cur[e] = o;
      o += len[e];
    }
  }
  __syncthreads();
  for (int s = tid; s < PADMAX; s += 256) perm[s] = -1;
  __syncthreads();
  for (int i = tid; i < TOK; i += 256) {
    const int e = eidx[i];
    const int p = atomicAdd(&cur[e], 1);
    perm[p] = i;
  }
  __syncthreads();
  for (int t = tid; t < NTILES; t += 256) {
    const int row = t * BM;
    int te = -1;
    for (int e = 0; e < NE; e++)
      if (row >= off[e] && row < off[e] + len[e]) te = e;
    tile_e[t] = te;
  }
}

// ---------------------------------------------------------------------------
// Kernel 2: transpose + convert weights: W [E][K][N] f32 -> WT [E][N][K] bf16
// v3: phase-2 widened to 16 B/granule (2x ds_read_b64 + global dwordx4),
// 4x fewer store instructions, 128-B dense write segments. Phase-1 identical.
// ---------------------------------------------------------------------------
__global__ __launch_bounds__(256)
void convtrans_kernel(const float* __restrict__ W, unsigned short* __restrict__ WT,
                      int K, int N) {
  __shared__ unsigned short T[64][68];   // 136-B rows: granules 8-B aligned
  const int e  = blockIdx.z;
  const int k0 = blockIdx.y * 64, n0 = blockIdx.x * 64;
  const float* Win = W + (size_t)e * K * N;
  unsigned short* Wout = WT + (size_t)e * K * N;
  const int tid = threadIdx.x;
  const int nl  = tid & 63;
  const int kb  = (tid >> 6) * 16;
#pragma unroll
  for (int r = 0; r < 16; r++) {
    const int kl = kb + r;
    T[nl][kl] = f2bf(Win[(size_t)(k0 + kl) * N + n0 + nl]);
  }
  __syncthreads();
  const int g  = tid & 7;    // k-granule (8 shorts = 16 B)
  const int nb = tid >> 3;   // 0..31
#pragma unroll
  for (int r = 0; r < 2; r++) {
    const int n = nb + 32 * r;
    const unsigned long long v0 = *(const unsigned long long*)&T[n][g * 8];
    const unsigned long long v1 = *(const unsigned long long*)&T[n][g * 8 + 4];
    ull2 o; o[0] = v0; o[1] = v1;
    *(ull2*)&Wout[(size_t)(n0 + n) * K + k0 + g * 8] = o;
  }
}

// ---------------------------------------------------------------------------
// Kernel 3: gather + convert x rows into permuted bf16 [PADMAX][DIM]
// ---------------------------------------------------------------------------
__global__ __launch_bounds__(256)
void xgather_kernel(const float* __restrict__ x, const int* __restrict__ perm,
                    unsigned short* __restrict__ xg) {
  const int slot = blockIdx.x;
  const int t    = perm[slot];
  const int tid  = threadIdx.x;
  ushort4v o = (ushort4v){0, 0, 0, 0};
  if (t >= 0) {
    const float4v v = *(const float4v*)(x + (size_t)t * DIM + tid * 4);
#pragma unroll
    for (int q = 0; q < 4; q++) o[q] = f2bf(v[q]);
  }
  *(ushort4v*)(xg + (size_t)slot * DIM + tid * 4) = o;
}

// ---------------------------------------------------------------------------
// Kernel 4: h = gelu(xg @ W1T^T + b1) -> bf16. 128x128 tile, BK=64,
// proven single-buffer schedule. NEW epilogue: fast-erf poly + LDS restage
// (reusing the 32 KB staging LDS) -> coalesced dwordx4 stores.
// Grid: (DMLP/BN, NTILES) col-fastest for XCD L2 reuse of B panels.
// ---------------------------------------------------------------------------
__global__ __launch_bounds__(256)
void gemm1_kernel(const unsigned short* __restrict__ xg,
                  const unsigned short* __restrict__ W1T,
                  const float* __restrict__ b1, const int* __restrict__ tile_e,
                  unsigned short* __restrict__ h) {
  const int bt = blockIdx.y;                 // row tile
  const int te = tile_e[bt];
  if (te < 0) return;
  const int n0 = blockIdx.x * BN;            // col tile
  const unsigned short* Asrc = xg + (size_t)bt * BM * DIM;
  const unsigned short* Bsrc = W1T + (size_t)te * DIM * DMLP + (size_t)n0 * DIM;
  const int tid = threadIdx.x;

  // single 32 KB pool: As = SMEM[0..8191], Bs = SMEM[8192..16383];
  // reused as the 128x128 bf16 h-tile in the epilogue.
  __shared__ __align__(16) unsigned short SMEM[BM * BK + BN * BK];

  // staging maps: issue t, this thread -> granule p = t*256+tid
  const unsigned short* ag[4];
  const unsigned short* bg[4];
  int lo[4];
#pragma unroll
  for (int t = 0; t < 4; t++) {
    const int p = t * 256 + tid;
    const int r = p >> 3;
    const int c = (p & 7) ^ (r & 7);
    ag[t] = Asrc + (size_t)r * DIM + c * 8;
    bg[t] = Bsrc + (size_t)r * DIM + c * 8;   // [N][K] rows: 128B segments
    lo[t] = p * 8;
  }

  const int wid = tid >> 6, lane = tid & 63;
  const int wm = (wid >> 1) * 64, wn = (wid & 1) * 64;
  const int l15 = lane & 15, quad = lane >> 4;

  float4v acc[4][4];
#pragma unroll
  for (int i = 0; i < 4; i++)
#pragma unroll
    for (int j = 0; j < 4; j++) acc[i][j] = (float4v){0.f, 0.f, 0.f, 0.f};

  for (int k0 = 0; k0 < DIM; k0 += BK) {
#pragma unroll
    for (int t = 0; t < 4; t++) ASYNC16(ag[t] + k0, &SMEM[lo[t]]);
#pragma unroll
    for (int t = 0; t < 4; t++) ASYNC16(bg[t] + k0, &SMEM[BM * BK + lo[t]]);
    __syncthreads();

#pragma unroll
    for (int hh = 0; hh < 2; hh++) {
      short8 a[4], b[4];
      const int C = hh * 4 + quad;
#pragma unroll
      for (int i = 0; i < 4; i++)
        a[i] = *(const short8*)&SMEM[FRAG_OFF(wm + i * 16 + l15, C)];
#pragma unroll
      for (int j = 0; j < 4; j++)
        b[j] = *(const short8*)&SMEM[BM * BK + FRAG_OFF(wn + j * 16 + l15, C)];
#pragma unroll
      for (int i = 0; i < 4; i++)
#pragma unroll
        for (int j = 0; j < 4; j++)
          acc[i][j] = __builtin_amdgcn_mfma_f32_16x16x32_bf16(a[i], b[j], acc[i][j], 0, 0, 0);
    }
    __syncthreads();
  }

  // ---- epilogue: gelu -> bf16 into LDS tile, then coalesced wide stores ----
#pragma unroll
  for (int i = 0; i < 4; i++) {
#pragma unroll
    for (int j = 0; j < 4; j++) {
      const int colL = wn + j * 16 + l15;        // tile-local col
      const float bias = b1[te * DMLP + n0 + colL];
#pragma unroll
      for (int r = 0; r < 4; r++) {
        const int rowL = wm + i * 16 + quad * 4 + r;
        SMEM[rowL * BN + colL] = f2bf(gelu_erf(acc[i][j][r] + bias));
      }
    }
  }
  __syncthreads();
  const int gg = tid & 15;       // 16-B granule within row
  const int rb = tid >> 4;       // row base 0..15
#pragma unroll
  for (int p = 0; p < 8; p++) {
    const int rowL = rb + p * 16;
    const ull2 v = *(const ull2*)&SMEM[rowL * BN + gg * 8];
    *(ull2*)&h[(size_t)(bt * BM + rowL) * DMLP + n0 + gg * 8] = v;
  }
}

// ---------------------------------------------------------------------------
// Kernel 5: out[tok] = h @ W2T^T + b2, scatter. 128x128 tile, BK=64,
// proven single-buffer schedule, unchanged from round 3.
// Grid: (DIM/BN = 8, NTILES) col-fastest.
// ---------------------------------------------------------------------------
__global__ __launch_bounds__(256)
void gemm2_kernel(const unsigned short* __restrict__ h,
                  const unsigned short* __restrict__ W2T,
                  const float* __restrict__ b2, const int* __restrict__ perm,
                  const int* __restrict__ tile_e, float* __restrict__ out) {
  const int bt = blockIdx.y;
  const int te = tile_e[bt];
  if (te < 0) return;
  const int n0 = blockIdx.x * BN;
  const unsigned short* Asrc = h + (size_t)bt * BM * DMLP;
  const unsigned short* Bsrc = W2T + (size_t)te * DMLP * DIM + (size_t)n0 * DMLP;
  const int tid = threadIdx.x;

  __shared__ __align__(16) unsigned short As[BM * BK];   // 16 KB
  __shared__ __align__(16) unsigned short Bs[BN * BK];   // 16 KB

  const unsigned short* ag[4];
  const unsigned short* bg[4];
  int lo[4];
#pragma unroll
  for (int t = 0; t < 4; t++) {
    const int p = t * 256 + tid;
    const int r = p >> 3;
    const int c = (p & 7) ^ (r & 7);
    ag[t] = Asrc + (size_t)r * DMLP + c * 8;
    bg[t] = Bsrc + (size_t)r * DMLP + c * 8;   // [N][K] rows: 128B segments
    lo[t] = p * 8;
  }

  const int wid = tid >> 6, lane = tid & 63;
  const int wm = (wid >> 1) * 64, wn = (wid & 1) * 64;
  const int l15 = lane & 15, quad = lane >> 4;

  float4v acc[4][4];
#pragma unroll
  for (int i = 0; i < 4; i++)
#pragma unroll
    for (int j = 0; j < 4; j++) acc[i][j] = (float4v){0.f, 0.f, 0.f, 0.f};

  for (int k0 = 0; k0 < DMLP; k0 += BK) {
#pragma unroll
    for (int t = 0; t < 4; t++) ASYNC16(ag[t] + k0, &As[lo[t]]);
#pragma unroll
    for (int t = 0; t < 4; t++) ASYNC16(bg[t] + k0, &Bs[lo[t]]);
    __syncthreads();

#pragma unroll
    for (int hh = 0; hh < 2; hh++) {
      short8 a[4], b[4];
      const int C = hh * 4 + quad;
#pragma unroll
      for (int i = 0; i < 4; i++) a[i] = *(const short8*)&As[FRAG_OFF(wm + i * 16 + l15, C)];
#pragma unroll
      for (int j = 0; j < 4; j++) b[j] = *(const short8*)&Bs[FRAG_OFF(wn + j * 16 + l15, C)];
#pragma unroll
      for (int i = 0; i < 4; i++)
#pragma unroll
        for (int j = 0; j < 4; j++)
          acc[i][j] = __builtin_amdgcn_mfma_f32_16x16x32_bf16(a[i], b[j], acc[i][j], 0, 0, 0);
    }
    __syncthreads();
  }

#pragma unroll
  for (int i = 0; i < 4; i++) {
#pragma unroll
    for (int j = 0; j < 4; j++) {
      const int col = n0 + wn + j * 16 + l15;
      const float bias = b2[te * DIM + col];
#pragma unroll
      for (int r = 0; r < 4; r++) {
        const int row  = wm + i * 16 + quad * 4 + r;
        const int slot = bt * BM + row;
        const int t    = perm[slot];
        if (t >= 0) out[(size_t)t * DIM + col] = acc[i][j][r] + bias;
      }
    }
  }
}

// ---------------------------------------------------------------------------
extern "C" void kernel_launch(void* const* d_in, const int* in_sizes, int n_in,
                              void* d_out, int out_size, void* d_ws, size_t ws_size,
                              hipStream_t stream) {
  const float* x    = (const float*)d_in[0];
  const int*   eidx = (const int*)d_in[1];
  const float* W1   = (const float*)d_in[2];
  const float* b1   = (const float*)d_in[3];
  const float* W2   = (const float*)d_in[4];
  const float* b2   = (const float*)d_in[5];
  float* out = (float*)d_out;

  char* ws = (char*)d_ws;
  int* perm   = (int*)ws;                              // PADMAX ints
  int* tile_e = (int*)(ws + PADMAX * sizeof(int));     // NTILES ints
  unsigned short* xg  = (unsigned short*)(ws + 32768);                      // 10 MB
  unsigned short* h   = (unsigned short*)(ws + 32768 + 10485760);           // 40 MB
  unsigned short* W1T = (unsigned short*)(ws + 32768 + 10485760 + 41943040);// 64 MB
  unsigned short* W2T = (unsigned short*)((char*)W1T + 67108864);           // 64 MB

  group_kernel<<<1, 256, 0, stream>>>(eidx, perm, tile_e);
  convtrans_kernel<<<dim3(DMLP / 64, DIM / 64, NE), 256, 0, stream>>>(W1, W1T, DIM, DMLP);
  convtrans_kernel<<<dim3(DIM / 64, DMLP / 64, NE), 256, 0, stream>>>(W2, W2T, DMLP, DIM);
  xgather_kernel<<<PADMAX, 256, 0, stream>>>(x, perm, xg);
  gemm1_kernel<<<dim3(DMLP / BN, NTILES), 256, 0, stream>>>(xg, W1T, b1, tile_e, h);
  gemm2_kernel<<<dim3(DIM / BN, NTILES), 256, 0, stream>>>(h, W2T, b2, perm, tile_e, out);
}

// Round 5
// 476.144 us; speedup vs baseline: 1.1677x; 1.0367x over previous
//
#include <hip/hip_runtime.h>
#include <hip/hip_bf16.h>
#include <math.h>

#define TOK   4096
#define DIM   1024
#define DMLP  4096
#define NE    8
#define BM    128
#define BN    128
#define BK    128
#define PADMAX (TOK + NE * BM)   // 5120 padded slots
#define NTILES (PADMAX / BM)     // 40 row-tiles

typedef __attribute__((ext_vector_type(8))) short  short8;
typedef __attribute__((ext_vector_type(4))) float  float4v;
typedef __attribute__((ext_vector_type(4))) unsigned short ushort4v;
typedef __attribute__((ext_vector_type(2))) unsigned long long ull2;

// async global->LDS, 16 B per lane; LDS dest is wave-uniform base + lane*16
#define ASYNC16(gp, lp) __builtin_amdgcn_global_load_lds( \
    (const __attribute__((address_space(1))) unsigned int*)(gp), \
    (__attribute__((address_space(3))) unsigned int*)(lp), 16, 0, 0)

// BK=128: 16 granules (8 bf16 = 16 B each) per row. Swizzle is an involution
// on the low 3 bits of the granule index; bank set depends only on low 3 bits
// -> ds_read_b128 by 16 lanes stays 2-way (free).
#define SWZ(R, C) (((C) & 8) | (((C) ^ (R)) & 7))
// LDS granule offset (in shorts) for row R, k-granule C
#define FRAG_OFF(R, C) ((((R) << 4) + SWZ(R, C)) << 3)

static __device__ __forceinline__ unsigned short f2bf(float f) {
  unsigned u = __float_as_uint(f);
  u += 0x7fffu + ((u >> 16) & 1u);
  return (unsigned short)(u >> 16);
}

// exact-erf GELU via Abramowitz&Stegun 7.1.26 (|err| < 1.5e-7)
static __device__ __forceinline__ float gelu_erf(float v) {
  const float x = fabsf(v) * 0.70710678118654752f;
  const float t = __builtin_amdgcn_rcpf(1.0f + 0.3275911f * x);
  const float poly = ((((1.061405429f * t - 1.453152027f) * t + 1.421413741f) * t
                       - 0.284496736f) * t + 0.254829592f) * t;
  const float erf_abs = 1.0f - poly * __expf(-x * x);
  return 0.5f * v * (1.0f + copysignf(erf_abs, v));
}

// ---------------------------------------------------------------------------
// Kernel 1: group tokens by expert (single block).
// ---------------------------------------------------------------------------
__global__ void group_kernel(const int* __restrict__ eidx,
                             int* __restrict__ perm,
                             int* __restrict__ tile_e) {
  __shared__ int cnt[NE], off[NE], len[NE], cur[NE];
  const int tid = threadIdx.x;
  if (tid < NE) cnt[tid] = 0;
  __syncthreads();
  for (int i = tid; i < TOK; i += 256) atomicAdd(&cnt[eidx[i]], 1);
  __syncthreads();
  if (tid == 0) {
    int o = 0;
    for (int e = 0; e < NE; e++) {
      off[e] = o;
      len[e] = ((cnt[e] + BM - 1) / BM) * BM;
      cur[e] = o;
      o += len[e];
    }
  }
  __syncthreads();
  for (int s = tid; s < PADMAX; s += 256) perm[s] = -1;
  __syncthreads();
  for (int i = tid; i < TOK; i += 256) {
    const int e = eidx[i];
    const int p = atomicAdd(&cur[e], 1);
    perm[p] = i;
  }
  __syncthreads();
  for (int t = tid; t < NTILES; t += 256) {
    const int row = t * BM;
    int te = -1;
    for (int e = 0; e < NE; e++)
      if (row >= off[e] && row < off[e] + len[e]) te = e;
    tile_e[t] = te;
  }
}

// ---------------------------------------------------------------------------
// Kernel 2: transpose + convert weights: W [E][K][N] f32 -> WT [E][N][K] bf16
// v4: phase-1 global reads vectorized to float4 (4 instrs/thread, 256-B
// segments); phase-2 16-B granule reads + dwordx4 stores (from r4).
// ---------------------------------------------------------------------------
__global__ __launch_bounds__(256)
void convtrans_kernel(const float* __restrict__ W, unsigned short* __restrict__ WT,
                      int K, int N) {
  __shared__ unsigned short T[64][68];   // pad 4: keeps 8-B align for phase-2
  const int e  = blockIdx.z;
  const int k0 = blockIdx.y * 64, n0 = blockIdx.x * 64;
  const float* Win = W + (size_t)e * K * N;
  unsigned short* Wout = WT + (size_t)e * K * N;
  const int tid = threadIdx.x;
  const int i4 = tid & 15;     // float4 column group
  const int kq = tid >> 4;     // 0..15
#pragma unroll
  for (int r = 0; r < 4; r++) {
    const int k = kq + 16 * r;
    const float4v v = *(const float4v*)(Win + (size_t)(k0 + k) * N + n0 + i4 * 4);
#pragma unroll
    for (int q = 0; q < 4; q++) T[i4 * 4 + q][k] = f2bf(v[q]);
  }
  __syncthreads();
  const int g  = tid & 7;    // k-granule (8 shorts = 16 B)
  const int nb = tid >> 3;   // 0..31
#pragma unroll
  for (int r = 0; r < 2; r++) {
    const int n = nb + 32 * r;
    const unsigned long long v0 = *(const unsigned long long*)&T[n][g * 8];
    const unsigned long long v1 = *(const unsigned long long*)&T[n][g * 8 + 4];
    ull2 o; o[0] = v0; o[1] = v1;
    *(ull2*)&Wout[(size_t)(n0 + n) * K + k0 + g * 8] = o;
  }
}

// ---------------------------------------------------------------------------
// Kernel 3: gather + convert x rows into permuted bf16 [PADMAX][DIM]
// ---------------------------------------------------------------------------
__global__ __launch_bounds__(256)
void xgather_kernel(const float* __restrict__ x, const int* __restrict__ perm,
                    unsigned short* __restrict__ xg) {
  const int slot = blockIdx.x;
  const int t    = perm[slot];
  const int tid  = threadIdx.x;
  ushort4v o = (ushort4v){0, 0, 0, 0};
  if (t >= 0) {
    const float4v v = *(const float4v*)(x + (size_t)t * DIM + tid * 4);
#pragma unroll
    for (int q = 0; q < 4; q++) o[q] = f2bf(v[q]);
  }
  *(ushort4v*)(xg + (size_t)slot * DIM + tid * 4) = o;
}

// ---------------------------------------------------------------------------
// Kernel 4: h = gelu(xg @ W1T^T + b1) -> bf16. 128x128 tile, BK=128
// (8 K-steps instead of 16: halves the per-step barrier-drain count, the
// measured bottleneck — duration was invariant to HBM traffic & occupancy).
// 64 KB LDS -> 2 blocks/CU (occupancy proven non-binding >=1.25).
// Grid: (DMLP/BN, NTILES) col-fastest for XCD L2 reuse of B panels.
// ---------------------------------------------------------------------------
__global__ __launch_bounds__(256)
void gemm1_kernel(const unsigned short* __restrict__ xg,
                  const unsigned short* __restrict__ W1T,
                  const float* __restrict__ b1, const int* __restrict__ tile_e,
                  unsigned short* __restrict__ h) {
  const int bt = blockIdx.y;                 // row tile
  const int te = tile_e[bt];
  if (te < 0) return;
  const int n0 = blockIdx.x * BN;            // col tile
  const unsigned short* Asrc = xg + (size_t)bt * BM * DIM;
  const unsigned short* Bsrc = W1T + (size_t)te * DIM * DMLP + (size_t)n0 * DIM;
  const int tid = threadIdx.x;

  // 64 KB pool: As = [0, 16384), Bs = [16384, 32768) shorts.
  // First 32 KB reused as the 128x128 bf16 h-tile in the epilogue.
  __shared__ __align__(16) unsigned short SMEM[2 * BM * BK];

  // staging map: granule p = t*256 + tid; r = p>>4 = 16t + (tid>>4),
  // q = p&15 = tid&15 (t-invariant) -> swizzled col t-invariant too.
  const int rr = tid >> 4, q = tid & 15;
  const int cs = SWZ(rr, q);
  const unsigned short* a0 = Asrc + (size_t)rr * DIM + cs * 8;
  const unsigned short* b0 = Bsrc + (size_t)rr * DIM + cs * 8;

  const int wid = tid >> 6, lane = tid & 63;
  const int wm = (wid >> 1) * 64, wn = (wid & 1) * 64;
  const int l15 = lane & 15, quad = lane >> 4;

  float4v acc[4][4];
#pragma unroll
  for (int i = 0; i < 4; i++)
#pragma unroll
    for (int j = 0; j < 4; j++) acc[i][j] = (float4v){0.f, 0.f, 0.f, 0.f};

  for (int k0 = 0; k0 < DIM; k0 += BK) {
#pragma unroll
    for (int t = 0; t < 8; t++)
      ASYNC16(a0 + (size_t)(16 * t) * DIM + k0, &SMEM[(t * 256 + tid) * 8]);
#pragma unroll
    for (int t = 0; t < 8; t++)
      ASYNC16(b0 + (size_t)(16 * t) * DIM + k0, &SMEM[BM * BK + (t * 256 + tid) * 8]);
    __syncthreads();

#pragma unroll
    for (int hh = 0; hh < 4; hh++) {
      short8 a[4], b[4];
      const int C = hh * 4 + quad;
#pragma unroll
      for (int i = 0; i < 4; i++)
        a[i] = *(const short8*)&SMEM[FRAG_OFF(wm + i * 16 + l15, C)];
#pragma unroll
      for (int j = 0; j < 4; j++)
        b[j] = *(const short8*)&SMEM[BM * BK + FRAG_OFF(wn + j * 16 + l15, C)];
#pragma unroll
      for (int i = 0; i < 4; i++)
#pragma unroll
        for (int j = 0; j < 4; j++)
          acc[i][j] = __builtin_amdgcn_mfma_f32_16x16x32_bf16(a[i], b[j], acc[i][j], 0, 0, 0);
    }
    __syncthreads();
  }

  // ---- epilogue: gelu -> bf16 into LDS tile, then coalesced wide stores ----
#pragma unroll
  for (int i = 0; i < 4; i++) {
#pragma unroll
    for (int j = 0; j < 4; j++) {
      const int colL = wn + j * 16 + l15;
      const float bias = b1[te * DMLP + n0 + colL];
#pragma unroll
      for (int r = 0; r < 4; r++) {
        const int rowL = wm + i * 16 + quad * 4 + r;
        SMEM[rowL * BN + colL] = f2bf(gelu_erf(acc[i][j][r] + bias));
      }
    }
  }
  __syncthreads();
  const int gg = tid & 15;       // 16-B granule within row
  const int rb = tid >> 4;       // row base 0..15
#pragma unroll
  for (int p = 0; p < 8; p++) {
    const int rowL = rb + p * 16;
    const ull2 v = *(const ull2*)&SMEM[rowL * BN + gg * 8];
    *(ull2*)&h[(size_t)(bt * BM + rowL) * DMLP + n0 + gg * 8] = v;
  }
}

// ---------------------------------------------------------------------------
// Kernel 5: out[tok] = h @ W2T^T + b2, scatter. 128x128 tile, BK=128
// (32 K-steps instead of 64). Grid: (DIM/BN = 8, NTILES) col-fastest.
// ---------------------------------------------------------------------------
__global__ __launch_bounds__(256)
void gemm2_kernel(const unsigned short* __restrict__ h,
                  const unsigned short* __restrict__ W2T,
                  const float* __restrict__ b2, const int* __restrict__ perm,
                  const int* __restrict__ tile_e, float* __restrict__ out) {
  const int bt = blockIdx.y;
  const int te = tile_e[bt];
  if (te < 0) return;
  const int n0 = blockIdx.x * BN;
  const unsigned short* Asrc = h + (size_t)bt * BM * DMLP;
  const unsigned short* Bsrc = W2T + (size_t)te * DMLP * DIM + (size_t)n0 * DMLP;
  const int tid = threadIdx.x;

  __shared__ __align__(16) unsigned short As[BM * BK];   // 32 KB
  __shared__ __align__(16) unsigned short Bs[BN * BK];   // 32 KB

  const int rr = tid >> 4, q = tid & 15;
  const int cs = SWZ(rr, q);
  const unsigned short* a0 = Asrc + (size_t)rr * DMLP + cs * 8;
  const unsigned short* b0 = Bsrc + (size_t)rr * DMLP + cs * 8;

  const int wid = tid >> 6, lane = tid & 63;
  const int wm = (wid >> 1) * 64, wn = (wid & 1) * 64;
  const int l15 = lane & 15, quad = lane >> 4;

  float4v acc[4][4];
#pragma unroll
  for (int i = 0; i < 4; i++)
#pragma unroll
    for (int j = 0; j < 4; j++) acc[i][j] = (float4v){0.f, 0.f, 0.f, 0.f};

  for (int k0 = 0; k0 < DMLP; k0 += BK) {
#pragma unroll
    for (int t = 0; t < 8; t++)
      ASYNC16(a0 + (size_t)(16 * t) * DMLP + k0, &As[(t * 256 + tid) * 8]);
#pragma unroll
    for (int t = 0; t < 8; t++)
      ASYNC16(b0 + (size_t)(16 * t) * DMLP + k0, &Bs[(t * 256 + tid) * 8]);
    __syncthreads();

#pragma unroll
    for (int hh = 0; hh < 4; hh++) {
      short8 a[4], b[4];
      const int C = hh * 4 + quad;
#pragma unroll
      for (int i = 0; i < 4; i++) a[i] = *(const short8*)&As[FRAG_OFF(wm + i * 16 + l15, C)];
#pragma unroll
      for (int j = 0; j < 4; j++) b[j] = *(const short8*)&Bs[FRAG_OFF(wn + j * 16 + l15, C)];
#pragma unroll
      for (int i = 0; i < 4; i++)
#pragma unroll
        for (int j = 0; j < 4; j++)
          acc[i][j] = __builtin_amdgcn_mfma_f32_16x16x32_bf16(a[i], b[j], acc[i][j], 0, 0, 0);
    }
    __syncthreads();
  }

#pragma unroll
  for (int i = 0; i < 4; i++) {
#pragma unroll
    for (int j = 0; j < 4; j++) {
      const int col = n0 + wn + j * 16 + l15;
      const float bias = b2[te * DIM + col];
#pragma unroll
      for (int r = 0; r < 4; r++) {
        const int row  = wm + i * 16 + quad * 4 + r;
        const int slot = bt * BM + row;
        const int t    = perm[slot];
        if (t >= 0) out[(size_t)t * DIM + col] = acc[i][j][r] + bias;
      }
    }
  }
}

// ---------------------------------------------------------------------------
extern "C" void kernel_launch(void* const* d_in, const int* in_sizes, int n_in,
                              void* d_out, int out_size, void* d_ws, size_t ws_size,
                              hipStream_t stream) {
  const float* x    = (const float*)d_in[0];
  const int*   eidx = (const int*)d_in[1];
  const float* W1   = (const float*)d_in[2];
  const float* b1   = (const float*)d_in[3];
  const float* W2   = (const float*)d_in[4];
  const float* b2   = (const float*)d_in[5];
  float* out = (float*)d_out;

  char* ws = (char*)d_ws;
  int* perm   = (int*)ws;                              // PADMAX ints
  int* tile_e = (int*)(ws + PADMAX * sizeof(int));     // NTILES ints
  unsigned short* xg  = (unsigned short*)(ws + 32768);                      // 10 MB
  unsigned short* h   = (unsigned short*)(ws + 32768 + 10485760);           // 40 MB
  unsigned short* W1T = (unsigned short*)(ws + 32768 + 10485760 + 41943040);// 64 MB
  unsigned short* W2T = (unsigned short*)((char*)W1T + 67108864);           // 64 MB

  group_kernel<<<1, 256, 0, stream>>>(eidx, perm, tile_e);
  convtrans_kernel<<<dim3(DMLP / 64, DIM / 64, NE), 256, 0, stream>>>(W1, W1T, DIM, DMLP);
  convtrans_kernel<<<dim3(DIM / 64, DMLP / 64, NE), 256, 0, stream>>>(W2, W2T, DMLP, DIM);
  xgather_kernel<<<PADMAX, 256, 0, stream>>>(x, perm, xg);
  gemm1_kernel<<<dim3(DMLP / BN, NTILES), 256, 0, stream>>>(xg, W1T, b1, tile_e, h);
  gemm2_kernel<<<dim3(DIM / BN, NTILES), 256, 0, stream>>>(h, W2T, b2, perm, tile_e, out);
}

// Round 6
// 468.969 us; speedup vs baseline: 1.1855x; 1.0153x over previous
//
#include <hip/hip_runtime.h>
#include <hip/hip_bf16.h>
#include <math.h>

#define TOK   4096
#define DIM   1024
#define DMLP  4096
#define NE    8
#define BM    128
#define BN    128
#define BN2   64
#define BK    128
#define PADMAX (TOK + NE * BM)   // 5120 padded slots
#define NTILES (PADMAX / BM)     // 40 row-tiles

typedef __attribute__((ext_vector_type(8))) short  short8;
typedef __attribute__((ext_vector_type(4))) float  float4v;
typedef __attribute__((ext_vector_type(4))) unsigned short ushort4v;
typedef __attribute__((ext_vector_type(2))) unsigned long long ull2;

// async global->LDS, 16 B per lane; LDS dest is wave-uniform base + lane*16
#define ASYNC16(gp, lp) __builtin_amdgcn_global_load_lds( \
    (const __attribute__((address_space(1))) unsigned int*)(gp), \
    (__attribute__((address_space(3))) unsigned int*)(lp), 16, 0, 0)

// BK=128: 16 granules (8 bf16 = 16 B each) per row. Involution on low 3 bits.
#define SWZ(R, C) (((C) & 8) | (((C) ^ (R)) & 7))
// LDS granule offset (in shorts) for row R, k-granule C
#define FRAG_OFF(R, C) ((((R) << 4) + SWZ(R, C)) << 3)

static __device__ __forceinline__ unsigned short f2bf(float f) {
  unsigned u = __float_as_uint(f);
  u += 0x7fffu + ((u >> 16) & 1u);
  return (unsigned short)(u >> 16);
}

// exact-erf GELU via Abramowitz&Stegun 7.1.26 (|err| < 1.5e-7)
static __device__ __forceinline__ float gelu_erf(float v) {
  const float x = fabsf(v) * 0.70710678118654752f;
  const float t = __builtin_amdgcn_rcpf(1.0f + 0.3275911f * x);
  const float poly = ((((1.061405429f * t - 1.453152027f) * t + 1.421413741f) * t
                       - 0.284496736f) * t + 0.254829592f) * t;
  const float erf_abs = 1.0f - poly * __expf(-x * x);
  return 0.5f * v * (1.0f + copysignf(erf_abs, v));
}

// ---------------------------------------------------------------------------
// Kernel 1: group tokens by expert (single block).
// ---------------------------------------------------------------------------
__global__ void group_kernel(const int* __restrict__ eidx,
                             int* __restrict__ perm,
                             int* __restrict__ tile_e) {
  __shared__ int cnt[NE], off[NE], len[NE], cur[NE];
  const int tid = threadIdx.x;
  if (tid < NE) cnt[tid] = 0;
  __syncthreads();
  for (int i = tid; i < TOK; i += 256) atomicAdd(&cnt[eidx[i]], 1);
  __syncthreads();
  if (tid == 0) {
    int o = 0;
    for (int e = 0; e < NE; e++) {
      off[e] = o;
      len[e] = ((cnt[e] + BM - 1) / BM) * BM;
      cur[e] = o;
      o += len[e];
    }
  }
  __syncthreads();
  for (int s = tid; s < PADMAX; s += 256) perm[s] = -1;
  __syncthreads();
  for (int i = tid; i < TOK; i += 256) {
    const int e = eidx[i];
    const int p = atomicAdd(&cur[e], 1);
    perm[p] = i;
  }
  __syncthreads();
  for (int t = tid; t < NTILES; t += 256) {
    const int row = t * BM;
    int te = -1;
    for (int e = 0; e < NE; e++)
      if (row >= off[e] && row < off[e] + len[e]) te = e;
    tile_e[t] = te;
  }
}

// ---------------------------------------------------------------------------
// Kernel 2: transpose + convert weights: W [E][K][N] f32 -> WT [E][N][K] bf16
// v5: phase-1 per thread = 4k x 4n f32 block (4x float4 coalesced loads)
// -> 4x ds_write_b64 (was 16x ds_write_b16). 4x fewer LDS write instrs;
// the kernel was measured issue-bound (load vectorization alone was neutral).
// Phase-2: 16-B granule reads + dwordx4 stores (unchanged).
// ---------------------------------------------------------------------------
__global__ __launch_bounds__(256)
void convtrans_kernel(const float* __restrict__ W, unsigned short* __restrict__ WT,
                      int K, int N) {
  __shared__ unsigned short T[64][68];   // 136-B rows; b64-aligned columns
  const int e  = blockIdx.z;
  const int k0 = blockIdx.y * 64, n0 = blockIdx.x * 64;
  const float* Win = W + (size_t)e * K * N;
  unsigned short* Wout = WT + (size_t)e * K * N;
  const int tid = threadIdx.x;
  const int i4 = tid & 15;          // n-quad: n = i4*4 + q
  const int kq = (tid >> 4) * 4;    // k base: 4 consecutive k
  float4v v[4];
#pragma unroll
  for (int j = 0; j < 4; j++)
    v[j] = *(const float4v*)(Win + (size_t)(k0 + kq + j) * N + n0 + i4 * 4);
#pragma unroll
  for (int q = 0; q < 4; q++) {
    ushort4v w;
#pragma unroll
    for (int j = 0; j < 4; j++) w[j] = f2bf(v[j][q]);
    *(ushort4v*)&T[i4 * 4 + q][kq] = w;
  }
  __syncthreads();
  const int g  = tid & 7;    // k-granule (8 shorts = 16 B)
  const int nb = tid >> 3;   // 0..31
#pragma unroll
  for (int r = 0; r < 2; r++) {
    const int n = nb + 32 * r;
    const unsigned long long v0 = *(const unsigned long long*)&T[n][g * 8];
    const unsigned long long v1 = *(const unsigned long long*)&T[n][g * 8 + 4];
    ull2 o; o[0] = v0; o[1] = v1;
    *(ull2*)&Wout[(size_t)(n0 + n) * K + k0 + g * 8] = o;
  }
}

// ---------------------------------------------------------------------------
// Kernel 3: gather + convert x rows into permuted bf16 [PADMAX][DIM]
// ---------------------------------------------------------------------------
__global__ __launch_bounds__(256)
void xgather_kernel(const float* __restrict__ x, const int* __restrict__ perm,
                    unsigned short* __restrict__ xg) {
  const int slot = blockIdx.x;
  const int t    = perm[slot];
  const int tid  = threadIdx.x;
  ushort4v o = (ushort4v){0, 0, 0, 0};
  if (t >= 0) {
    const float4v v = *(const float4v*)(x + (size_t)t * DIM + tid * 4);
#pragma unroll
    for (int q = 0; q < 4; q++) o[q] = f2bf(v[q]);
  }
  *(ushort4v*)(xg + (size_t)slot * DIM + tid * 4) = o;
}

// ---------------------------------------------------------------------------
// Kernel 4: h = gelu(xg @ W1T^T + b1) -> bf16. 128x128 tile, BK=128
// (unchanged from round 5: 8 K-steps, 64 KB LDS, 2 blocks/CU, grid even
// at 5 blocks/CU). Grid: (DMLP/BN, NTILES) col-fastest for XCD L2 reuse.
// ---------------------------------------------------------------------------
__global__ __launch_bounds__(256)
void gemm1_kernel(const unsigned short* __restrict__ xg,
                  const unsigned short* __restrict__ W1T,
                  const float* __restrict__ b1, const int* __restrict__ tile_e,
                  unsigned short* __restrict__ h) {
  const int bt = blockIdx.y;                 // row tile
  const int te = tile_e[bt];
  if (te < 0) return;
  const int n0 = blockIdx.x * BN;            // col tile
  const unsigned short* Asrc = xg + (size_t)bt * BM * DIM;
  const unsigned short* Bsrc = W1T + (size_t)te * DIM * DMLP + (size_t)n0 * DIM;
  const int tid = threadIdx.x;

  __shared__ __align__(16) unsigned short SMEM[2 * BM * BK];

  const int rr = tid >> 4, q = tid & 15;
  const int cs = SWZ(rr, q);
  const unsigned short* a0 = Asrc + (size_t)rr * DIM + cs * 8;
  const unsigned short* b0 = Bsrc + (size_t)rr * DIM + cs * 8;

  const int wid = tid >> 6, lane = tid & 63;
  const int wm = (wid >> 1) * 64, wn = (wid & 1) * 64;
  const int l15 = lane & 15, quad = lane >> 4;

  float4v acc[4][4];
#pragma unroll
  for (int i = 0; i < 4; i++)
#pragma unroll
    for (int j = 0; j < 4; j++) acc[i][j] = (float4v){0.f, 0.f, 0.f, 0.f};

  for (int k0 = 0; k0 < DIM; k0 += BK) {
#pragma unroll
    for (int t = 0; t < 8; t++)
      ASYNC16(a0 + (size_t)(16 * t) * DIM + k0, &SMEM[(t * 256 + tid) * 8]);
#pragma unroll
    for (int t = 0; t < 8; t++)
      ASYNC16(b0 + (size_t)(16 * t) * DIM + k0, &SMEM[BM * BK + (t * 256 + tid) * 8]);
    __syncthreads();

#pragma unroll
    for (int hh = 0; hh < 4; hh++) {
      short8 a[4], b[4];
      const int C = hh * 4 + quad;
#pragma unroll
      for (int i = 0; i < 4; i++)
        a[i] = *(const short8*)&SMEM[FRAG_OFF(wm + i * 16 + l15, C)];
#pragma unroll
      for (int j = 0; j < 4; j++)
        b[j] = *(const short8*)&SMEM[BM * BK + FRAG_OFF(wn + j * 16 + l15, C)];
#pragma unroll
      for (int i = 0; i < 4; i++)
#pragma unroll
        for (int j = 0; j < 4; j++)
          acc[i][j] = __builtin_amdgcn_mfma_f32_16x16x32_bf16(a[i], b[j], acc[i][j], 0, 0, 0);
    }
    __syncthreads();
  }

  // ---- epilogue: gelu -> bf16 into LDS tile, then coalesced wide stores ----
#pragma unroll
  for (int i = 0; i < 4; i++) {
#pragma unroll
    for (int j = 0; j < 4; j++) {
      const int colL = wn + j * 16 + l15;
      const float bias = b1[te * DMLP + n0 + colL];
#pragma unroll
      for (int r = 0; r < 4; r++) {
        const int rowL = wm + i * 16 + quad * 4 + r;
        SMEM[rowL * BN + colL] = f2bf(gelu_erf(acc[i][j][r] + bias));
      }
    }
  }
  __syncthreads();
  const int gg = tid & 15;       // 16-B granule within row
  const int rb = tid >> 4;       // row base 0..15
#pragma unroll
  for (int p = 0; p < 8; p++) {
    const int rowL = rb + p * 16;
    const ull2 v = *(const ull2*)&SMEM[rowL * BN + gg * 8];
    *(ull2*)&h[(size_t)(bt * BM + rowL) * DMLP + n0 + gg * 8] = v;
  }
}

// ---------------------------------------------------------------------------
// Kernel 5: out[tok] = h @ W2T^T + b2, scatter. 128x64 tile, BK=128.
// LDS 48 KB -> 3 blocks/CU; grid (DIM/64, NTILES) = 640 blocks -> all
// co-resident, balance 3-vs-2 (was 2-vs-1 with 320 blocks at 2/CU).
// ---------------------------------------------------------------------------
__global__ __launch_bounds__(256)
void gemm2_kernel(const unsigned short* __restrict__ h,
                  const unsigned short* __restrict__ W2T,
                  const float* __restrict__ b2, const int* __restrict__ perm,
                  const int* __restrict__ tile_e, float* __restrict__ out) {
  const int bt = blockIdx.y;
  const int te = tile_e[bt];
  if (te < 0) return;
  const int n0 = blockIdx.x * BN2;
  const unsigned short* Asrc = h + (size_t)bt * BM * DMLP;
  const unsigned short* Bsrc = W2T + (size_t)te * DMLP * DIM + (size_t)n0 * DMLP;
  const int tid = threadIdx.x;

  __shared__ __align__(16) unsigned short As[BM * BK];    // 32 KB
  __shared__ __align__(16) unsigned short Bs[BN2 * BK];   // 16 KB

  const int rr = tid >> 4, q = tid & 15;
  const int cs = SWZ(rr, q);
  const unsigned short* a0 = Asrc + (size_t)rr * DMLP + cs * 8;
  const unsigned short* b0 = Bsrc + (size_t)rr * DMLP + cs * 8;

  const int wid = tid >> 6, lane = tid & 63;
  const int wm = (wid >> 1) * 64, wn = (wid & 1) * 32;
  const int l15 = lane & 15, quad = lane >> 4;

  float4v acc[4][2];
#pragma unroll
  for (int i = 0; i < 4; i++)
#pragma unroll
    for (int j = 0; j < 2; j++) acc[i][j] = (float4v){0.f, 0.f, 0.f, 0.f};

  for (int k0 = 0; k0 < DMLP; k0 += BK) {
#pragma unroll
    for (int t = 0; t < 8; t++)
      ASYNC16(a0 + (size_t)(16 * t) * DMLP + k0, &As[(t * 256 + tid) * 8]);
#pragma unroll
    for (int t = 0; t < 4; t++)
      ASYNC16(b0 + (size_t)(16 * t) * DMLP + k0, &Bs[(t * 256 + tid) * 8]);
    __syncthreads();

#pragma unroll
    for (int hh = 0; hh < 4; hh++) {
      short8 a[4], b[2];
      const int C = hh * 4 + quad;
#pragma unroll
      for (int i = 0; i < 4; i++) a[i] = *(const short8*)&As[FRAG_OFF(wm + i * 16 + l15, C)];
#pragma unroll
      for (int j = 0; j < 2; j++) b[j] = *(const short8*)&Bs[FRAG_OFF(wn + j * 16 + l15, C)];
#pragma unroll
      for (int i = 0; i < 4; i++)
#pragma unroll
        for (int j = 0; j < 2; j++)
          acc[i][j] = __builtin_amdgcn_mfma_f32_16x16x32_bf16(a[i], b[j], acc[i][j], 0, 0, 0);
    }
    __syncthreads();
  }

#pragma unroll
  for (int i = 0; i < 4; i++) {
#pragma unroll
    for (int j = 0; j < 2; j++) {
      const int col = n0 + wn + j * 16 + l15;
      const float bias = b2[te * DIM + col];
#pragma unroll
      for (int r = 0; r < 4; r++) {
        const int row  = wm + i * 16 + quad * 4 + r;
        const int slot = bt * BM + row;
        const int t    = perm[slot];
        if (t >= 0) out[(size_t)t * DIM + col] = acc[i][j][r] + bias;
      }
    }
  }
}

// ---------------------------------------------------------------------------
extern "C" void kernel_launch(void* const* d_in, const int* in_sizes, int n_in,
                              void* d_out, int out_size, void* d_ws, size_t ws_size,
                              hipStream_t stream) {
  const float* x    = (const float*)d_in[0];
  const int*   eidx = (const int*)d_in[1];
  const float* W1   = (const float*)d_in[2];
  const float* b1   = (const float*)d_in[3];
  const float* W2   = (const float*)d_in[4];
  const float* b2   = (const float*)d_in[5];
  float* out = (float*)d_out;

  char* ws = (char*)d_ws;
  int* perm   = (int*)ws;                              // PADMAX ints
  int* tile_e = (int*)(ws + PADMAX * sizeof(int));     // NTILES ints
  unsigned short* xg  = (unsigned short*)(ws + 32768);                      // 10 MB
  unsigned short* h   = (unsigned short*)(ws + 32768 + 10485760);           // 40 MB
  unsigned short* W1T = (unsigned short*)(ws + 32768 + 10485760 + 41943040);// 64 MB
  unsigned short* W2T = (unsigned short*)((char*)W1T + 67108864);           // 64 MB

  group_kernel<<<1, 256, 0, stream>>>(eidx, perm, tile_e);
  convtrans_kernel<<<dim3(DMLP / 64, DIM / 64, NE), 256, 0, stream>>>(W1, W1T, DIM, DMLP);
  convtrans_kernel<<<dim3(DIM / 64, DMLP / 64, NE), 256, 0, stream>>>(W2, W2T, DMLP, DIM);
  xgather_kernel<<<PADMAX, 256, 0, stream>>>(x, perm, xg);
  gemm1_kernel<<<dim3(DMLP / BN, NTILES), 256, 0, stream>>>(xg, W1T, b1, tile_e, h);
  gemm2_kernel<<<dim3(DIM / BN2, NTILES), 256, 0, stream>>>(h, W2T, b2, perm, tile_e, out);
}